// Round 2
// baseline (419.344 us; speedup 1.0000x reference)
//
#include <hip/hip_runtime.h>
#include <math.h>

// SparseCoding, round 15.
// R14 post-mortem: wall identical to R13 (244 us) despite moving the GEMM to
// MFMA. Two causes found in counters: (1) __launch_bounds__(512,2) capped
// VGPRs at 128 -> ~100 regs spilled to scratch, re-read every iter (the +13MB
// WRITE_SIZE); (2) the per-iteration cross-block loss transport: gcnt packs 16
// windows (8 XCDs) per 64B line -> 64 atomics + 64 pollers ping-pong the line
// through L3/HBM every iteration (~7 us/iter floor, invariant to inner work).
// R15 removes both:
//  * ONE BLOCK = ONE WINDOW (32 rows). Grid still 256 for the Gram phase
//    (1 row/block); blocks 63..255 exit. Loss reduction is entirely LDS-local:
//    gpart/gcnt/sxbuf and all per-iteration global atomics/spins are GONE.
//    Lag-2 verdict machinery preserved exactly via the parity ring s_redq[2][].
//  * A-stack is 64x256 bf16 (rows 0-31 coef-hi, 32-63 coef-lo). In the 16x16
//    C layout, hi-tile row r and lo-tile row r map to the same lane/reg, so
//    all four split products (Ahi+Alo)@(Ghi+Glo) accumulate into ONE acc:
//    a4 = acc[pp][T][t] directly - no shuffles, no duplicate lanes; each
//    thread owns exactly 16 coefs.
//  * __launch_bounds__(512,1): 256 VGPR/wave; 8 waves x 256 = 2048 = full CU
//    pool, block still resident. G frags (128 VGPR) now truly live in regs.
//  * cfp eliminated: on stop, previous coef is reconstructed exactly by
//    undoing one Adam step from retained m,v,b1p,b2p (same fast-math ops).
#define NB     256
#define NF     128
#define FT     1024
#define NW     63
#define TORIG  256
#define RPB    8
#define GRID   256

using f32x4  = __attribute__((ext_vector_type(4))) float;
using bf16x8 = __attribute__((ext_vector_type(8))) short;

// setup xB exchange layout (float4 index): k2*512 + row*64 + (cg ^ row)
__device__ __forceinline__ int xidx(int k2, int cg, int row) {
    return (k2 * 512 + row * 64 + (cg ^ row)) * 4;
}

// round-to-nearest-even fp32 -> bf16 bits (upper 16)
__device__ __forceinline__ unsigned bf16_hi(float x) {
    const unsigned u = __float_as_uint(x);
    return (u + 0x7fffu + ((u >> 16) & 1u)) >> 16;
}

__global__ __launch_bounds__(512, 1) void window_kernel(
    const float* __restrict__ spec,
    const float* __restrict__ basis,
    float* __restrict__ G,               // ws: 256x256
    const int* __restrict__ p_niter,
    const int* __restrict__ p_pad,
    const int* __restrict__ p_stride,
    unsigned int* __restrict__ gbar,     // single word, memset 0
    float* __restrict__ out)             // (32,256,63)
{
    // Arena: [0,32K) A0 | [32K,64K) A1 | [64K,96K) s_xn; s_p0 aliases [0,64K)
    // (setup-only, dead before A0/A1 first write).
    __shared__ __align__(16) char arena[98304];
    short* const A0   = (short*)arena;             // 64x256 bf16 stacked coef
    short* const A1   = (short*)(arena + 32768);
    float* const s_xn = (float*)(arena + 65536);   // 8x1024 staging (per group)
    float* const s_p0 = (float*)arena;             // 64KB xB exchange (setup)
    __shared__ __align__(16) float s_xb[32 * NB];  // 32KB xB results
    __shared__ float  s_gred[2][NB];
    __shared__ float  s_mn[RPB], s_rng[RPB];
    __shared__ double s_dred[8];
    __shared__ double s_sx;
    __shared__ float  s_redq[2][8], s_redr[2][8];
    __shared__ int    s_stop[2];

    const int bid = blockIdx.x;
    const int tid = threadIdx.x;
    const int ks  = tid >> 6;                    // wave index
    const int kg  = tid & 63;
    const int r   = kg >> 3;                     // setup-phase owned row
    const int cgo = 8 * ks + (kg & 7);           // setup-phase owned colgroup
    const int n_iter = p_niter[0];

    // ================= fused Gram: block bid computes G row bid ==================
    {
        const int c = tid & 255, jh = tid >> 8;
        float acc = 0.f;
        const float* bp = basis + (size_t)(jh * 512) * NB;
        #pragma unroll 16
        for (int j = 0; j < 512; ++j)
            acc = fmaf(bp[j * NB + bid], bp[j * NB + c], acc);
        s_gred[jh][c] = acc;
        __syncthreads();
        if (jh == 0) G[(size_t)bid * NB + c] = s_gred[0][c] + s_gred[1][c];
    }
    __threadfence();
    __syncthreads();
    if (tid == 0) atomicAdd(gbar, 1u);
    if (bid >= NW) return;                       // 193 blocks exit after Gram

    const int w  = bid;
    const int t0 = w * p_stride[0] - p_pad[0];
    if (tid == 0) s_sx = 0.0;                    // single-writer; barriers order

    // ======== setup per 8-row group: stage, normalize, xB (R13 VALU path) =======
    #pragma unroll 1
    for (int rg = 0; rg < 4; ++rg) {
        #pragma unroll
        for (int i = 0; i < 16; ++i) {
            const int e = i * 512 + tid;
            const int b = e >> 10, jj = e & 1023;
            const int f = jj >> 3, t = jj & 7, tq = t0 + t;
            s_xn[b * FT + jj] = (tq >= 0 && tq < TORIG)
                ? spec[((size_t)(rg * RPB + b) * NF + f) * TORIG + tq] : 0.f;
        }
        __syncthreads();
        {   // wave ks scans row ks
            float mn = __builtin_inff(), mx = -__builtin_inff();
            #pragma unroll
            for (int i = 0; i < 16; ++i) {
                const float v = s_xn[ks * FT + i * 64 + kg];
                mn = fminf(mn, v); mx = fmaxf(mx, v);
            }
            #pragma unroll
            for (int off = 32; off; off >>= 1) {
                mn = fminf(mn, __shfl_down(mn, off));
                mx = fmaxf(mx, __shfl_down(mx, off));
            }
            if (kg == 0) { s_mn[ks] = mn; s_rng[ks] = mx - mn; }
        }
        __syncthreads();
        double sx2p = 0.0;
        #pragma unroll
        for (int i = 0; i < 16; ++i) {
            const int e = i * 512 + tid;
            const int b = e >> 10, jj = e & 1023;
            const float v = (s_xn[b * FT + jj] - s_mn[b]) / s_rng[b];
            s_xn[b * FT + jj] = v;
            sx2p += (double)v * (double)v;
        }
        #pragma unroll
        for (int off = 32; off; off >>= 1) sx2p += __shfl_down(sx2p, off);
        if (kg == 0) s_dred[ks] = sx2p;
        __syncthreads();
        if (tid == 0) {
            double s = 0.0;
            #pragma unroll
            for (int i = 0; i < 8; ++i) s += s_dred[i];
            s_sx += s;
        }

        // xB = xnorm @ basis, K-split partials (bit-identical R13 arithmetic)
        float xbp[RPB][4];
        #pragma unroll
        for (int b = 0; b < RPB; ++b)
            #pragma unroll
            for (int j = 0; j < 4; ++j) xbp[b][j] = 0.f;
        for (int i0 = 0; i0 < 128; i0 += 4) {
            const int jj = ks * 128 + i0;
            float4 bv[4];
            #pragma unroll
            for (int t = 0; t < 4; ++t)
                bv[t] = *(const float4*)(basis + (size_t)(jj + t) * NB + 4 * kg);
            #pragma unroll
            for (int b = 0; b < RPB; ++b) {
                const float4 x4 = *(const float4*)&s_xn[b * FT + jj];
                xbp[b][0] = fmaf(x4.x, bv[0].x, fmaf(x4.y, bv[1].x, fmaf(x4.z, bv[2].x, fmaf(x4.w, bv[3].x, xbp[b][0]))));
                xbp[b][1] = fmaf(x4.x, bv[0].y, fmaf(x4.y, bv[1].y, fmaf(x4.z, bv[2].y, fmaf(x4.w, bv[3].y, xbp[b][1]))));
                xbp[b][2] = fmaf(x4.x, bv[0].z, fmaf(x4.y, bv[1].z, fmaf(x4.z, bv[2].z, fmaf(x4.w, bv[3].z, xbp[b][2]))));
                xbp[b][3] = fmaf(x4.x, bv[0].w, fmaf(x4.y, bv[1].w, fmaf(x4.z, bv[2].w, fmaf(x4.w, bv[3].w, xbp[b][3]))));
            }
        }
        __syncthreads();
        #pragma unroll
        for (int b = 0; b < RPB; ++b)
            *(float4*)&s_p0[xidx(ks, kg, b)] =
                make_float4(xbp[b][0], xbp[b][1], xbp[b][2], xbp[b][3]);
        __syncthreads();
        float xBo[4] = {0.f, 0.f, 0.f, 0.f};
        #pragma unroll
        for (int k2 = 0; k2 < 8; ++k2) {
            const float4 p4 = *(const float4*)&s_p0[xidx(k2, cgo, r)];
            xBo[0] += p4.x; xBo[1] += p4.y; xBo[2] += p4.z; xBo[3] += p4.w;
        }
        *(float4*)&s_xb[(size_t)(rg * RPB + r) * NB + 4 * cgo] =
            make_float4(xBo[0], xBo[1], xBo[2], xBo[3]);
    }

    // ================= wait for G; init block-local state ========================
    if (tid == 0) {
        while (__hip_atomic_load(gbar, __ATOMIC_ACQUIRE, __HIP_MEMORY_SCOPE_AGENT) < (unsigned)GRID)
            __builtin_amdgcn_s_sleep(1);
    }
    if (tid == 64) { s_stop[0] = 0; s_stop[1] = 0; }
    __syncthreads();   // also: last s_p0 read done block-wide -> A0/A1 safe

    // ============== MFMA-layout ownership & fragment constants ===================
    const int lr = kg & 15;          // C col within 16-tile
    const int lh = kg >> 4;          // lane group 0..3 -> C rows 4lh..4lh+3

    // G B-fragments, hi/lo bf16 split. B layout: col = lane&15, k = 8*(lane>>4)+b.
    bf16x8 Gh[8][2], Gl[8][2];
    {
        const float* gp = G + (size_t)(8 * lh) * NB + 32 * ks + lr;
        #pragma unroll
        for (int kk = 0; kk < 8; ++kk)
            #pragma unroll
            for (int T = 0; T < 2; ++T)
                #pragma unroll
                for (int b = 0; b < 8; ++b) {
                    const float gv = gp[(size_t)(32 * kk + b) * NB + 16 * T];
                    const unsigned hb = bf16_hi(gv);
                    const float    hf = __uint_as_float(hb << 16);
                    const unsigned lb = bf16_hi(gv - hf);
                    Gh[kk][T][b] = (short)hb;
                    Gl[kk][T][b] = (short)lb;
                }
    }

    // owned xB (16 coefs: pp in {0,1} row blocks, T in {0,1} col tiles, t=reg)
    float xB[16];
    #pragma unroll
    for (int pp = 0; pp < 2; ++pp)
        #pragma unroll
        for (int T = 0; T < 2; ++T)
            #pragma unroll
            for (int t = 0; t < 4; ++t)
                xB[pp * 8 + T * 4 + t] =
                    s_xb[(size_t)(16 * pp + 4 * lh + t) * NB + 32 * ks + 16 * T + lr];

    // A tile: 64 rows x 256 cols bf16; row = 16*Mt + (lane&15) for reads.
    // Swizzle: short-idx ^= (row&7)<<3 (16B granule spread).
    const int base0 = lr * 256 + 8 * lh;         // read base (shorts)
    const int swz   = (lr & 7) << 3;

    // ================= init owned coef / Adam; write A0 ==========================
    const float C0 = 0.5f / 256.f;
    float cf[16], m_[16], v_[16];
    #pragma unroll
    for (int j = 0; j < 16; ++j) { cf[j] = C0; m_[j] = 0.f; v_[j] = 0.f; }
    {
        const short vh = (short)bf16_hi(C0);     // C0 = 2^-9 exact, lo = 0
        #pragma unroll
        for (int pp = 0; pp < 2; ++pp)
            #pragma unroll
            for (int T = 0; T < 2; ++T)
                #pragma unroll
                for (int t = 0; t < 4; ++t) {
                    const int rr = 16 * pp + 4 * lh + t;
                    const int cc = 32 * ks + 16 * T + lr;
                    const int wb = ((rr * 256 + cc) ^ ((rr & 7) << 3)) << 1;
                    *(short*)((char*)A0 + wb)         = vh;   // hi row
                    *(short*)((char*)A0 + wb + 16384) = 0;    // lo row (+32 rows)
                }
    }
    float b1p = 1.f, b2p = 1.f;
    float old_loss = 1e-10f;      // tid64 only
    double sxtot = 0.0;           // tid64 only
    const float c1c = 2.f / 32768.f, c2c = 0.2f / 8192.f;
    int use_prev = 0;

    for (int it = 0; it < n_iter; ++it) {
        const int p = it & 1;
        const char* rdb = (const char*)(p ? A1 : A0);
        char*       wrb = (char*)(p ? A0 : A1);

        __syncthreads();          // barrier 1: A[rdb] writes (prev iter) visible

        // ---- MFMA: (Ahi+Alo) @ (Ghi+Glo), all 4 terms into one acc ----
        f32x4 acc[2][2];
        const f32x4 z4 = {0.f, 0.f, 0.f, 0.f};
        acc[0][0] = z4; acc[0][1] = z4; acc[1][0] = z4; acc[1][1] = z4;
        #pragma unroll
        for (int kk = 0; kk < 8; ++kk) {
            #pragma unroll
            for (int pp = 0; pp < 2; ++pp) {
                const int o = base0 + pp * 4096 + kk * 32;
                const bf16x8 ah = *(const bf16x8*)(rdb + ((o ^ swz) << 1));
                const bf16x8 al = *(const bf16x8*)(rdb + (((o + 8192) ^ swz) << 1));
                acc[pp][0] = __builtin_amdgcn_mfma_f32_16x16x32_bf16(ah, Gh[kk][0], acc[pp][0], 0, 0, 0);
                acc[pp][1] = __builtin_amdgcn_mfma_f32_16x16x32_bf16(ah, Gh[kk][1], acc[pp][1], 0, 0, 0);
                acc[pp][0] = __builtin_amdgcn_mfma_f32_16x16x32_bf16(al, Gh[kk][0], acc[pp][0], 0, 0, 0);
                acc[pp][1] = __builtin_amdgcn_mfma_f32_16x16x32_bf16(al, Gh[kk][1], acc[pp][1], 0, 0, 0);
                acc[pp][0] = __builtin_amdgcn_mfma_f32_16x16x32_bf16(ah, Gl[kk][0], acc[pp][0], 0, 0, 0);
                acc[pp][1] = __builtin_amdgcn_mfma_f32_16x16x32_bf16(ah, Gl[kk][1], acc[pp][1], 0, 0, 0);
                acc[pp][0] = __builtin_amdgcn_mfma_f32_16x16x32_bf16(al, Gl[kk][0], acc[pp][0], 0, 0, 0);
                acc[pp][1] = __builtin_amdgcn_mfma_f32_16x16x32_bf16(al, Gl[kk][1], acc[pp][1], 0, 0, 0);
            }
        }

        // ---- tid64: LAG-2 consume, all LDS-local (parity ring = lag-2 store) ----
        if (tid == 64 && it >= 2) {
            const int itc = it - 2;
            double Qt = 0.0, Rt = 0.0;
            #pragma unroll
            for (int i = 0; i < 8; ++i) {
                Qt += (double)s_redq[p][i];
                Rt += (double)s_redr[p][i];
            }
            if (itc == 0) sxtot = s_sx;
            const float loss = (float)((Qt + sxtot) / 32768.0 + 0.2 * (Rt / 8192.0));
            const float stat = fabsf(old_loss - loss) / old_loss;
            old_loss = loss;
            s_stop[p] = (stat < 1e-3f) ? 1 : 0;
        }

        __syncthreads();          // barrier 2: s_stop[p] + s_redq[p] consume done

        if (s_stop[p]) { use_prev = 1; break; }   // answer = coef before last step

        // ---- loss partials -> parity ring (block-local; no atomics) ----
        if (it + 1 < n_iter) {
            float qc = 0.f, rr_ = 0.f;
            #pragma unroll
            for (int j = 0; j < 16; ++j) {
                const float a4v = acc[j >> 3][(j >> 2) & 1][j & 3];
                qc += cf[j] * (a4v - 2.f * xB[j]);
                rr_ += fabsf(cf[j]);
            }
            #pragma unroll
            for (int off = 32; off; off >>= 1) {
                qc  += __shfl_down(qc, off);
                rr_ += __shfl_down(rr_, off);
            }
            if (kg == 0) { s_redq[p][ks] = qc; s_redr[p][ks] = rr_; }
        }

        // ---- Adam update (fast rcp/sqrt) ----
        b1p *= 0.9f; b2p *= 0.999f;
        const float rb1 = __builtin_amdgcn_rcpf(1.f - b1p);
        const float rb2 = __builtin_amdgcn_rcpf(1.f - b2p);
        #pragma unroll
        for (int j = 0; j < 16; ++j) {
            const float a4v = acc[j >> 3][(j >> 2) & 1][j & 3];
            const float c_  = cf[j];
            const float sgn = (c_ > 0.f) ? 1.f : ((c_ < 0.f) ? -1.f : 0.f);
            const float gg  = c1c * (a4v - xB[j]) + c2c * sgn;
            m_[j] = 0.9f * m_[j] + 0.1f * gg;
            v_[j] = 0.999f * v_[j] + 0.001f * gg * gg;
            const float den = __builtin_amdgcn_sqrtf(v_[j] * rb2) + 1e-8f;
            cf[j] = c_ - 1e-3f * (m_[j] * rb1) * __builtin_amdgcn_rcpf(den);
        }

        // ---- bf16 hi/lo split of new coef -> next A buffer ----
        #pragma unroll
        for (int pp = 0; pp < 2; ++pp)
            #pragma unroll
            for (int T = 0; T < 2; ++T)
                #pragma unroll
                for (int t = 0; t < 4; ++t) {
                    const int j  = pp * 8 + T * 4 + t;
                    const int rr = 16 * pp + 4 * lh + t;
                    const int cc = 32 * ks + 16 * T + lr;
                    const int wb = ((rr * 256 + cc) ^ ((rr & 7) << 3)) << 1;
                    const unsigned hb = bf16_hi(cf[j]);
                    const float    hf = __uint_as_float(hb << 16);
                    const unsigned lb = bf16_hi(cf[j] - hf);
                    *(short*)(wrb + wb)         = (short)hb;
                    *(short*)(wrb + wb + 16384) = (short)lb;
                }
    }

    // ---- post-loop consume round: conv at t = n_iter-2 (if not already stopped) ----
    if (!use_prev && n_iter >= 2) {
        if (tid == 64) {
            const int itc = n_iter - 2;
            const int pc  = itc & 1;
            double Qt = 0.0, Rt = 0.0;
            #pragma unroll
            for (int i = 0; i < 8; ++i) {
                Qt += (double)s_redq[pc][i];
                Rt += (double)s_redr[pc][i];
            }
            if (itc == 0) sxtot = s_sx;
            const float loss = (float)((Qt + sxtot) / 32768.0 + 0.2 * (Rt / 8192.0));
            const float stat = fabsf(old_loss - loss) / old_loss;
            s_stop[0] = (stat < 1e-3f) ? 1 : 0;
        }
        __syncthreads();
        use_prev = s_stop[0];
    }

    // ---- output; on stop reconstruct pre-step coef by exact Adam-step undo ----
    {
        const float rb1e = __builtin_amdgcn_rcpf(1.f - b1p);
        const float rb2e = __builtin_amdgcn_rcpf(1.f - b2p);
        #pragma unroll
        for (int pp = 0; pp < 2; ++pp)
            #pragma unroll
            for (int T = 0; T < 2; ++T)
                #pragma unroll
                for (int t = 0; t < 4; ++t) {
                    const int j = pp * 8 + T * 4 + t;
                    float val = cf[j];
                    if (use_prev) {
                        const float den = __builtin_amdgcn_sqrtf(v_[j] * rb2e) + 1e-8f;
                        val += 1e-3f * (m_[j] * rb1e) * __builtin_amdgcn_rcpf(den);
                    }
                    out[((size_t)(16 * pp + 4 * lh + t) * NB + 32 * ks + 16 * T + lr) * NW + w] = val;
                }
    }
}

// ---------------------------------------------------------------------------
extern "C" void kernel_launch(void* const* d_in, const int* in_sizes, int n_in,
                              void* d_out, int out_size, void* d_ws, size_t ws_size,
                              hipStream_t stream)
{
    const float* spec   = (const float*)d_in[0];
    const float* basis  = (const float*)d_in[1];
    const int* p_niter  = (const int*)d_in[2];
    const int* p_pad    = (const int*)d_in[3];
    const int* p_stride = (const int*)d_in[4];
    float* out = (float*)d_out;

    char* ws = (char*)d_ws;
    float*        G    = (float*)ws;                 // 256 KB
    unsigned int* gbar = (unsigned int*)(ws + 262144);

    hipMemsetAsync(gbar, 0, sizeof(unsigned int), stream);
    window_kernel<<<dim3(GRID), dim3(512), 0, stream>>>(
        spec, basis, G, p_niter, p_pad, p_stride, gbar, out);
}